// Round 1
// baseline (1398.194 us; speedup 1.0000x reference)
//
#include <hip/hip_runtime.h>

#define N_DIM 32768
#define K_DIM 4096
#define D_DIM 512

typedef __attribute__((ext_vector_type(8))) short short8;
typedef __attribute__((ext_vector_type(4))) float f32x4;

// ---------------------------------------------------------------- helpers

__device__ __forceinline__ unsigned short f32_to_bf16_rne(float f) {
  unsigned int u = __builtin_bit_cast(unsigned int, f);
  u += 0x7fffu + ((u >> 16) & 1u);   // round-to-nearest-even (inputs finite)
  return (unsigned short)(u >> 16);
}

__device__ __forceinline__ void gl2lds16(const void* g, void* l) {
  // async global->LDS, 16B per lane; LDS dest = wave-uniform base + lane*16
  __builtin_amdgcn_global_load_lds(
      (const __attribute__((address_space(1))) unsigned int*)g,
      (__attribute__((address_space(3))) unsigned int*)l, 16, 0, 0);
}

// ---------------------------------------------------------------- kernel 0/1: fp32 -> bf16

__global__ __launch_bounds__(256) void cvt_bf16(const float* __restrict__ in,
                                                unsigned short* __restrict__ out,
                                                int n4) {
  int i = blockIdx.x * 256 + threadIdx.x;
  if (i < n4) {
    float4 f = ((const float4*)in)[i];
    ushort4 u;
    u.x = f32_to_bf16_rne(f.x);
    u.y = f32_to_bf16_rne(f.y);
    u.z = f32_to_bf16_rne(f.z);
    u.w = f32_to_bf16_rne(f.w);
    ((ushort4*)out)[i] = u;
  }
}

// ---------------------------------------------------------------- kernel 2: bf16 MFMA GEMM (C = A * B^T)
// A: [N][D] bf16, B: [K][D] bf16 (both row-major, shared inner dim D) -> C [N][K] fp32
// 128x128 tile, BK=32, 4 waves each computing a 64x64 quadrant via 4x4 of 16x16x32 MFMA.

__global__ __launch_bounds__(256) void gemm_bf16(const unsigned short* __restrict__ A,
                                                 const unsigned short* __restrict__ B,
                                                 float* __restrict__ C) {
  __shared__ __align__(16) short As[128 * 32];  // rows of 32 bf16 (64 B), no pad (global_load_lds layout)
  __shared__ __align__(16) short Bs[128 * 32];

  const int tid = threadIdx.x;
  const int l   = tid & 63;
  const int w   = tid >> 6;        // wave 0..3
  const int wr  = w >> 1;          // quadrant row (0/1)
  const int wc  = w & 1;           // quadrant col (0/1)
  const int m   = l & 15;          // fragment row/col within 16
  const int q   = l >> 4;          // quad 0..3

  const int blockCol = blockIdx.x * 128;  // codes (K dim)
  const int blockRow = blockIdx.y * 128;  // z rows (N dim)

  // staging: 8 wave-loads of 1KB per operand; wave w does slots w and w+4.
  const int lrow   = l >> 2;        // 16 rows per 1KB slot
  const int lchunk = (l & 3) * 8;   // 4 chunks of 8 bf16 per 64B row
  const unsigned short* ga0 = A + (size_t)(blockRow + w * 16 + lrow) * D_DIM + lchunk;
  const unsigned short* ga1 = ga0 + (size_t)64 * D_DIM;
  const unsigned short* gb0 = B + (size_t)(blockCol + w * 16 + lrow) * D_DIM + lchunk;
  const unsigned short* gb1 = gb0 + (size_t)64 * D_DIM;
  short* la0 = As + w * 512;
  short* la1 = As + (w + 4) * 512;
  short* lb0 = Bs + w * 512;
  short* lb1 = Bs + (w + 4) * 512;

  f32x4 acc[4][4] = {};

  for (int k0 = 0; k0 < D_DIM; k0 += 32) {
    gl2lds16(ga0, la0);
    gl2lds16(ga1, la1);
    gl2lds16(gb0, lb0);
    gl2lds16(gb1, lb1);
    __syncthreads();   // barrier drains vmcnt -> LDS data visible

    short8 af[4], bfr[4];
#pragma unroll
    for (int mi = 0; mi < 4; mi++)
      af[mi] = *(const short8*)(As + (wr * 64 + mi * 16 + m) * 32 + q * 8);
#pragma unroll
    for (int ni = 0; ni < 4; ni++)
      bfr[ni] = *(const short8*)(Bs + (wc * 64 + ni * 16 + m) * 32 + q * 8);

#pragma unroll
    for (int mi = 0; mi < 4; mi++)
#pragma unroll
      for (int ni = 0; ni < 4; ni++)
        acc[mi][ni] = __builtin_amdgcn_mfma_f32_16x16x32_bf16(af[mi], bfr[ni], acc[mi][ni], 0, 0, 0);

    __syncthreads();   // protect LDS before next staging overwrite
    ga0 += 32; ga1 += 32; gb0 += 32; gb1 += 32;
  }

  // epilogue: C/D layout col = lane&15, row = quad*4 + reg  [m89/m91-verified]
#pragma unroll
  for (int mi = 0; mi < 4; mi++) {
#pragma unroll
    for (int r = 0; r < 4; r++) {
      const int row = blockRow + wr * 64 + mi * 16 + q * 4 + r;
      float* crow = C + (size_t)row * K_DIM + blockCol + wc * 64 + m;
#pragma unroll
      for (int ni = 0; ni < 4; ni++) crow[ni * 16] = acc[mi][ni][r];
    }
  }
}

// ---------------------------------------------------------------- kernel 3: per-row argmax with exact fp64 refinement
// One block (256 thr) per row: find approx row max, then for every logit within
// DELTA of it recompute the exact dot from the fp32 inputs in fp64; argmax those.

#define DELTA 6.0e-4f

__global__ __launch_bounds__(256) void argmax_refine(const float* __restrict__ logits,
                                                     const float* __restrict__ Z,
                                                     const float* __restrict__ CB,
                                                     float* __restrict__ outIdx) {
  const int row = blockIdx.x;
  const int t   = threadIdx.x;
  const float4* lr = (const float4*)(logits + (size_t)row * K_DIM);

  float4 v[4];
  float lmax = -3.0e38f;
#pragma unroll
  for (int i = 0; i < 4; i++) {
    v[i] = lr[t + 256 * i];
    lmax = fmaxf(lmax, fmaxf(fmaxf(v[i].x, v[i].y), fmaxf(v[i].z, v[i].w)));
  }
#pragma unroll
  for (int off = 32; off >= 1; off >>= 1) lmax = fmaxf(lmax, __shfl_xor(lmax, off));

  __shared__ float wm[4];
  if ((t & 63) == 0) wm[t >> 6] = lmax;
  __syncthreads();
  const float thresh = fmaxf(fmaxf(wm[0], wm[1]), fmaxf(wm[2], wm[3])) - DELTA;

  double bestv = -1.0e300;
  int    besti = 0x7fffffff;
  const float* zr = Z + (size_t)row * D_DIM;
#pragma unroll
  for (int i = 0; i < 4; i++) {
    const float vv[4] = {v[i].x, v[i].y, v[i].z, v[i].w};
    for (int j = 0; j < 4; j++) {
      if (vv[j] >= thresh) {     // rare: ~1.8 candidates per row
        const int k = (t + 256 * i) * 4 + j;
        const float* br = CB + (size_t)k * D_DIM;
        double s = 0.0;
        for (int d = 0; d < D_DIM; d++) s += (double)zr[d] * (double)br[d];
        if (s > bestv || (s == bestv && k < besti)) { bestv = s; besti = k; }
      }
    }
  }

  __shared__ double sv[256];
  __shared__ int    si[256];
  sv[t] = bestv; si[t] = besti;
  __syncthreads();
  for (int s = 128; s > 0; s >>= 1) {
    if (t < s) {
      if (sv[t + s] > sv[t] || (sv[t + s] == sv[t] && si[t + s] < si[t])) {
        sv[t] = sv[t + s]; si[t] = si[t + s];
      }
    }
    __syncthreads();
  }
  if (t == 0) outIdx[row] = (float)si[0];
}

// ---------------------------------------------------------------- launch

extern "C" void kernel_launch(void* const* d_in, const int* in_sizes, int n_in,
                              void* d_out, int out_size, void* d_ws, size_t ws_size,
                              hipStream_t stream) {
  const float* Z  = (const float*)d_in[0];   // [N][D] fp32
  const float* CB = (const float*)d_in[1];   // [K][D] fp32
  float* out = (float*)d_out;                // [N*K logits][N indices-as-float]

  unsigned short* Abf = (unsigned short*)d_ws;                              // 32 MiB
  unsigned short* Bbf = (unsigned short*)d_ws + (size_t)N_DIM * D_DIM;      // +4 MiB

  cvt_bf16<<<(N_DIM * D_DIM / 4) / 256, 256, 0, stream>>>(Z, Abf, N_DIM * D_DIM / 4);
  cvt_bf16<<<(K_DIM * D_DIM / 4) / 256, 256, 0, stream>>>(CB, Bbf, K_DIM * D_DIM / 4);

  dim3 grid(K_DIM / 128, N_DIM / 128);
  gemm_bf16<<<grid, 256, 0, stream>>>(Abf, Bbf, out);

  argmax_refine<<<N_DIM, 256, 0, stream>>>(out, Z, CB, out + (size_t)N_DIM * K_DIM);
}

// Round 2
// 868.938 us; speedup vs baseline: 1.6091x; 1.6091x over previous
//
#include <hip/hip_runtime.h>

#define N_DIM 32768
#define K_DIM 4096
#define D_DIM 512

typedef __attribute__((ext_vector_type(8))) short short8;
typedef __attribute__((ext_vector_type(4))) float f32x4;

// ---------------------------------------------------------------- helpers

__device__ __forceinline__ unsigned short f32_to_bf16_rne(float f) {
  unsigned int u = __builtin_bit_cast(unsigned int, f);
  u += 0x7fffu + ((u >> 16) & 1u);   // round-to-nearest-even (inputs finite)
  return (unsigned short)(u >> 16);
}

__device__ __forceinline__ void gl2lds16(const void* g, void* l) {
  // async global->LDS, 16B per lane; LDS dest = wave-uniform base + lane*16
  __builtin_amdgcn_global_load_lds(
      (const __attribute__((address_space(1))) unsigned int*)g,
      (__attribute__((address_space(3))) unsigned int*)l, 16, 0, 0);
}

// ---------------------------------------------------------------- kernel 0/1: fp32 -> bf16

__global__ __launch_bounds__(256) void cvt_bf16(const float* __restrict__ in,
                                                unsigned short* __restrict__ out,
                                                int n4) {
  int i = blockIdx.x * 256 + threadIdx.x;
  if (i < n4) {
    float4 f = ((const float4*)in)[i];
    ushort4 u;
    u.x = f32_to_bf16_rne(f.x);
    u.y = f32_to_bf16_rne(f.y);
    u.z = f32_to_bf16_rne(f.z);
    u.w = f32_to_bf16_rne(f.w);
    ((ushort4*)out)[i] = u;
  }
}

// ---------------------------------------------------------------- kernel 2: bf16 MFMA GEMM (C = A * B^T)
// A: [N][D] bf16, B: [K][D] bf16 (both row-major, shared inner dim D) -> C [N][K] fp32
// 128x128 tile, BK=32, 4 waves each computing a 64x64 quadrant via 4x4 of 16x16x32 MFMA.

__global__ __launch_bounds__(256) void gemm_bf16(const unsigned short* __restrict__ A,
                                                 const unsigned short* __restrict__ B,
                                                 float* __restrict__ C) {
  __shared__ __align__(16) short As[128 * 32];  // rows of 32 bf16 (64 B), no pad (global_load_lds layout)
  __shared__ __align__(16) short Bs[128 * 32];

  const int tid = threadIdx.x;
  const int l   = tid & 63;
  const int w   = tid >> 6;        // wave 0..3
  const int wr  = w >> 1;          // quadrant row (0/1)
  const int wc  = w & 1;           // quadrant col (0/1)
  const int m   = l & 15;          // fragment row/col within 16
  const int q   = l >> 4;          // quad 0..3

  const int blockCol = blockIdx.x * 128;  // codes (K dim)
  const int blockRow = blockIdx.y * 128;  // z rows (N dim)

  // staging: 8 wave-loads of 1KB per operand; wave w does slots w and w+4.
  const int lrow   = l >> 2;        // 16 rows per 1KB slot
  const int lchunk = (l & 3) * 8;   // 4 chunks of 8 bf16 per 64B row
  const unsigned short* ga0 = A + (size_t)(blockRow + w * 16 + lrow) * D_DIM + lchunk;
  const unsigned short* ga1 = ga0 + (size_t)64 * D_DIM;
  const unsigned short* gb0 = B + (size_t)(blockCol + w * 16 + lrow) * D_DIM + lchunk;
  const unsigned short* gb1 = gb0 + (size_t)64 * D_DIM;
  short* la0 = As + w * 512;
  short* la1 = As + (w + 4) * 512;
  short* lb0 = Bs + w * 512;
  short* lb1 = Bs + (w + 4) * 512;

  f32x4 acc[4][4] = {};

  for (int k0 = 0; k0 < D_DIM; k0 += 32) {
    gl2lds16(ga0, la0);
    gl2lds16(ga1, la1);
    gl2lds16(gb0, lb0);
    gl2lds16(gb1, lb1);
    __syncthreads();   // barrier drains vmcnt -> LDS data visible

    short8 af[4], bfr[4];
#pragma unroll
    for (int mi = 0; mi < 4; mi++)
      af[mi] = *(const short8*)(As + (wr * 64 + mi * 16 + m) * 32 + q * 8);
#pragma unroll
    for (int ni = 0; ni < 4; ni++)
      bfr[ni] = *(const short8*)(Bs + (wc * 64 + ni * 16 + m) * 32 + q * 8);

#pragma unroll
    for (int mi = 0; mi < 4; mi++)
#pragma unroll
      for (int ni = 0; ni < 4; ni++)
        acc[mi][ni] = __builtin_amdgcn_mfma_f32_16x16x32_bf16(af[mi], bfr[ni], acc[mi][ni], 0, 0, 0);

    __syncthreads();   // protect LDS before next staging overwrite
    ga0 += 32; ga1 += 32; gb0 += 32; gb1 += 32;
  }

  // epilogue: C/D layout col = lane&15, row = quad*4 + reg  [m89/m91-verified]
#pragma unroll
  for (int mi = 0; mi < 4; mi++) {
#pragma unroll
    for (int r = 0; r < 4; r++) {
      const int row = blockRow + wr * 64 + mi * 16 + q * 4 + r;
      float* crow = C + (size_t)row * K_DIM + blockCol + wc * 64 + m;
#pragma unroll
      for (int ni = 0; ni < 4; ni++) crow[ni * 16] = acc[mi][ni][r];
    }
  }
}

// ---------------------------------------------------------------- kernel 3: per-row argmax with exact fp64 refinement
// One block (256 thr) per row. Phase 1: vector read of the row, block max.
// Phase 2: candidates within DELTA of max -> LDS list (~2.8 per row expected).
// Phase 3: ONE WAVE PER CANDIDATE recomputes the exact fp64 dot from the fp32
// inputs (64 lanes x 8 elems, coalesced float4 loads, shuffle reduce) — this
// replaces R1's single-lane rolled loop that was ~150k cycles of serialized
// load latency per block.

#define DELTA 6.0e-4f
#define MAXCAND 64

__global__ __launch_bounds__(256) void argmax_refine(const float* __restrict__ logits,
                                                     const float* __restrict__ Z,
                                                     const float* __restrict__ CB,
                                                     float* __restrict__ outIdx) {
  const int row  = blockIdx.x;
  const int t    = threadIdx.x;
  const int lane = t & 63;
  const int w    = t >> 6;

  const float4* lr = (const float4*)(logits + (size_t)row * K_DIM);

  // ---- phase 1: row max
  float4 v[4];
  float lmax = -3.0e38f;
#pragma unroll
  for (int i = 0; i < 4; i++) {
    v[i] = lr[t + 256 * i];
    lmax = fmaxf(lmax, fmaxf(fmaxf(v[i].x, v[i].y), fmaxf(v[i].z, v[i].w)));
  }
#pragma unroll
  for (int off = 32; off >= 1; off >>= 1) lmax = fmaxf(lmax, __shfl_xor(lmax, off));

  __shared__ float wm[4];
  if (lane == 0) wm[w] = lmax;
  __syncthreads();
  const float thresh = fmaxf(fmaxf(wm[0], wm[1]), fmaxf(wm[2], wm[3])) - DELTA;

  // ---- phase 2: collect candidates into LDS
  __shared__ int cand[MAXCAND];
  __shared__ int ccount;
  if (t == 0) ccount = 0;
  __syncthreads();
#pragma unroll
  for (int i = 0; i < 4; i++) {
    const float vv[4] = {v[i].x, v[i].y, v[i].z, v[i].w};
#pragma unroll
    for (int j = 0; j < 4; j++) {
      if (vv[j] >= thresh) {
        int idx = atomicAdd(&ccount, 1);
        if (idx < MAXCAND) cand[idx] = (t + 256 * i) * 4 + j;
      }
    }
  }
  __syncthreads();
  const int nc = min(ccount, MAXCAND);

  // ---- phase 3: exact fp64 dot per candidate, one wave per candidate
  __shared__ double cval[MAXCAND];
  const float4* zr4 = (const float4*)(Z + (size_t)row * D_DIM);
  for (int c = w; c < nc; c += 4) {
    const int k = cand[c];
    const float4* br4 = (const float4*)(CB + (size_t)k * D_DIM);
    float4 z0 = zr4[lane], z1 = zr4[lane + 64];
    float4 b0 = br4[lane], b1 = br4[lane + 64];
    double s = (double)z0.x * b0.x + (double)z0.y * b0.y +
               (double)z0.z * b0.z + (double)z0.w * b0.w +
               (double)z1.x * b1.x + (double)z1.y * b1.y +
               (double)z1.z * b1.z + (double)z1.w * b1.w;
#pragma unroll
    for (int off = 32; off >= 1; off >>= 1) s += __shfl_xor(s, off);
    if (lane == 0) cval[c] = s;
  }
  __syncthreads();

  if (t == 0) {
    double best = -1.0e300;
    int    bi   = 0x7fffffff;
    for (int c = 0; c < nc; c++) {
      if (cval[c] > best || (cval[c] == best && cand[c] < bi)) {
        best = cval[c];
        bi   = cand[c];
      }
    }
    outIdx[row] = (float)bi;
  }
}

// ---------------------------------------------------------------- launch

extern "C" void kernel_launch(void* const* d_in, const int* in_sizes, int n_in,
                              void* d_out, int out_size, void* d_ws, size_t ws_size,
                              hipStream_t stream) {
  const float* Z  = (const float*)d_in[0];   // [N][D] fp32
  const float* CB = (const float*)d_in[1];   // [K][D] fp32
  float* out = (float*)d_out;                // [N*K logits][N indices-as-float]

  unsigned short* Abf = (unsigned short*)d_ws;                              // 32 MiB
  unsigned short* Bbf = (unsigned short*)d_ws + (size_t)N_DIM * D_DIM;      // +4 MiB

  cvt_bf16<<<(N_DIM * D_DIM / 4) / 256, 256, 0, stream>>>(Z, Abf, N_DIM * D_DIM / 4);
  cvt_bf16<<<(K_DIM * D_DIM / 4) / 256, 256, 0, stream>>>(CB, Bbf, K_DIM * D_DIM / 4);

  dim3 grid(K_DIM / 128, N_DIM / 128);
  gemm_bf16<<<grid, 256, 0, stream>>>(Abf, Bbf, out);

  argmax_refine<<<N_DIM, 256, 0, stream>>>(out, Z, CB, out + (size_t)N_DIM * K_DIM);
}